// Round 2
// 59.664 us; speedup vs baseline: 1.0388x; 1.0388x over previous
//
#include <hip/hip_runtime.h>
#include <math.h>

// Problem constants (from setup_inputs): B=4, C=4, H=96, W=96
#define BB 4
#define CC 4
#define HH 96
#define WW 96
#define NN (HH * WW)
#define WPR (WW / 4)          // 24 u32 words per row
#define NW (NN / 4)           // 2304 words per image
#define BIGF 1e10f
#define OROWS (HH / 8)        // 12 rows per block octant

// ---------------------------------------------------------------------------
// K1: one block per (batch b, direction e, octant o). blk = b*16 + e*8 + o
//   e=0: EDT of maskP, masked max over maskT pixels (bwd)
//   e=1: EDT of maskT, masked max over maskP pixels (fwd)
// All intermediates in LDS.
// R8/R9 (resubmit after infra failure): pred+tgt nibble-packed into ONE LDS
// image word -> P2 does one neighbor-read set for both masks; P3a (column-bit
// transpose pass + barrier) folded into P2 via lane-staggered LDS atomicOr;
// wave-uniform skip of the w2 ghost loads; tournament argmax; wave-parallel
// k_fin.
// History: cooperative launch +23 µs (R4); in-kernel atomic finalize
// neutral-to-worse (R6); early-exit P4 −4 µs (R7).
// ---------------------------------------------------------------------------
__global__ __launch_bounds__(1024) void k_fused(const float* __restrict__ out,
                                                const int* __restrict__ tgt,
                                                float* __restrict__ partial) {
    // LDS carve, 57,280 B used. Region A (36864 B) is time-shared:
    //   P1/P2: comb (9216, pred|tgt nibble-packed);  P3b/P4: gq (36864, fp32 EDT)
    __shared__ __align__(16) unsigned char smem[57344];
    unsigned int* comb    = (unsigned int*)smem;           //  9216 B (dead after P2)
    float* gq             = (float*)smem;                  // 36864 B (live from P3b)
    unsigned char* maskE  = smem + 36864;                  //  9216 B
    unsigned char* maskO  = smem + 46080;                  //  9216 B
    unsigned int* colbits = (unsigned int*)(smem + 55296); //  1920 B (stride 5)
    float* red            = (float*)(smem + 57216);        //    64 B

    const int blk = blockIdx.x;
    const int oct = blk & 7;
    const int e = (blk >> 3) & 1;
    const int b = blk >> 4;
    const int tid = threadIdx.x;

    // colbits zero-init (filled by atomicOr in P2). Ordered by the P1 barrier.
    if (tid < 96 * 5) colbits[tid] = 0;

    // ---- P1: argmax over C (first-max) + nibble-pack pred|tgt<<4 per byte ----
    // NW = 2304 = 2*1024 + 256: every thread does w0,w1; tid<256 also w2
    // (wave-uniform branch: waves 4..15 issue no ghost loads).
    const float* o0 = out + (size_t)b * CC * NN;
    const float* o1 = o0 + NN;
    const float* o2 = o0 + 2 * NN;
    const float* o3 = o0 + 3 * NN;
    const int* tbase = tgt + b * NN;
    {
        const int w0 = tid, w1 = tid + 1024, w2 = tid + 2048;
        const bool has2 = (tid < NW - 2048);          // tid < 256: wave-uniform
        const int p0 = w0 * 4, p1 = w1 * 4, p2 = w2 * 4;

        // issue all global loads before any LDS write
        float4 a0 = *(const float4*)(o0 + p0);
        float4 a1 = *(const float4*)(o1 + p0);
        float4 a2 = *(const float4*)(o2 + p0);
        float4 a3 = *(const float4*)(o3 + p0);
        float4 b0 = *(const float4*)(o0 + p1);
        float4 b1 = *(const float4*)(o1 + p1);
        float4 b2 = *(const float4*)(o2 + p1);
        float4 b3 = *(const float4*)(o3 + p1);
        int4 t0 = *(const int4*)(tbase + p0);
        int4 t1 = *(const int4*)(tbase + p1);
        float4 c0, c1, c2, c3;
        int4 t2;
        if (has2) {
            c0 = *(const float4*)(o0 + p2);
            c1 = *(const float4*)(o1 + p2);
            c2 = *(const float4*)(o2 + p2);
            c3 = *(const float4*)(o3 + p2);
            t2 = *(const int4*)(tbase + p2);
        }

        // tournament argmax, first-max semantics (matches jnp.argmax):
        // ties resolved toward lower index via strict-> comparisons.
        #define AMAX4(v0, v1, v2, v3, sh, pk) {                          \
            bool c01 = (v1) > (v0); float lo_ = c01 ? (v1) : (v0);       \
            bool c23 = (v3) > (v2); float hi_ = c23 ? (v3) : (v2);       \
            unsigned int id = (hi_ > lo_) ? (2u | (unsigned int)c23)     \
                                          : (unsigned int)c01;           \
            pk |= id << (sh); }
        unsigned int pk0 = 0, pk1 = 0;
        AMAX4(a0.x, a1.x, a2.x, a3.x, 0,  pk0) AMAX4(a0.y, a1.y, a2.y, a3.y, 8,  pk0)
        AMAX4(a0.z, a1.z, a2.z, a3.z, 16, pk0) AMAX4(a0.w, a1.w, a2.w, a3.w, 24, pk0)
        AMAX4(b0.x, b1.x, b2.x, b3.x, 0,  pk1) AMAX4(b0.y, b1.y, b2.y, b3.y, 8,  pk1)
        AMAX4(b0.z, b1.z, b2.z, b3.z, 16, pk1) AMAX4(b0.w, b1.w, b2.w, b3.w, 24, pk1)

        unsigned int tw0 = (t0.x & 3) | ((t0.y & 3) << 8) | ((t0.z & 3) << 16) | ((t0.w & 3) << 24);
        unsigned int tw1 = (t1.x & 3) | ((t1.y & 3) << 8) | ((t1.z & 3) << 16) | ((t1.w & 3) << 24);
        comb[w0] = pk0 | (tw0 << 4);   // byte = pred(bits0-1) | tgt(bits4-5)
        comb[w1] = pk1 | (tw1 << 4);
        if (has2) {
            unsigned int pk2 = 0;
            AMAX4(c0.x, c1.x, c2.x, c3.x, 0,  pk2) AMAX4(c0.y, c1.y, c2.y, c3.y, 8,  pk2)
            AMAX4(c0.z, c1.z, c2.z, c3.z, 16, pk2) AMAX4(c0.w, c1.w, c2.w, c3.w, 24, pk2)
            unsigned int tw2 = (t2.x & 3) | ((t2.y & 3) << 8) | ((t2.z & 3) << 16) | ((t2.w & 3) << 24);
            comb[w2] = pk2 | (tw2 << 4);
        }
        #undef AMAX4
    }
    __syncthreads();

    // ---- P2: both boundary masks from ONE neighbor-read set (4 px/thread),
    //          column bitmasks of maskE built inline via LDS atomicOr ----
    {
        const unsigned int* iw = comb;
        const int kst = tid & 3;                 // lane stagger for atomicOr banks
        auto PROC = [&](int w) {
            int i = w / WPR;
            int jw = w - i * WPR;
            unsigned int c = iw[w];
            unsigned int diff = 0;
            if (i > 0)      diff |= c ^ iw[w - WPR];
            if (i < HH - 1) diff |= c ^ iw[w + WPR];
            unsigned int l = (c << 8) | (jw > 0 ? (iw[w - 1] >> 24) : (c & 0xFFu));
            diff |= c ^ l;
            unsigned int r = (c >> 8) | (jw < WPR - 1 ? (iw[w + 1] << 24) : (c & 0xFF000000u));
            diff |= c ^ r;
            // per-byte: low nibble nonzero -> pred boundary, high nibble -> tgt
            unsigned int dL = diff & 0x0F0F0F0Fu;
            unsigned int dH = (diff >> 4) & 0x0F0F0F0Fu;
            unsigned int mP = ((dL + 0x0F0F0F0Fu) >> 4) & 0x01010101u;
            unsigned int mT = ((dH + 0x0F0F0F0Fu) >> 4) & 0x01010101u;
            unsigned int mE = e ? mT : mP;
            ((unsigned int*)maskE)[w] = mE;
            ((unsigned int*)maskO)[w] = e ? mP : mT;
            // fold former P3a: set column bits of maskE
            int widx = i >> 5;
            unsigned int bit = 1u << (i & 31);
            #pragma unroll
            for (int kk = 0; kk < 4; ++kk) {
                int k = (kk + kst) & 3;          // spread banks across lanes
                if ((mE >> (8 * k)) & 1u)
                    atomicOr(&colbits[(jw * 4 + k) * 5 + widx], bit);
            }
        };
        PROC(tid);
        PROC(tid + 1024);
        if (tid < NW - 2048) PROC(tid + 2048);
    }
    __syncthreads();   // maskE/maskO/colbits ready; comb dead from here

    // ---- P3b: column EDT via clz/ffs — ONLY this block's octant rows ----
    const int pix0 = oct * OROWS * WW;        // this block's 1152 pixels
    for (int p4 = tid; p4 < OROWS * WW; p4 += 1024) {
        int p = pix0 + p4;
        int i = p / WW;
        int j = p - i * WW;
        unsigned int w0 = colbits[j * 5 + 0];
        unsigned int w1 = colbits[j * 5 + 1];
        unsigned int hi = colbits[j * 5 + 2];
        unsigned long long lo = (unsigned long long)w0 | ((unsigned long long)w1 << 32);
        int up = 1 << 20, dn = 1 << 20;
        if (i < 64) {
            unsigned long long mu = lo & (~0ull >> (63 - i));          // rows 0..i
            if (mu) up = i - (63 - __clzll(mu));
            unsigned long long md = lo >> i;                           // rows i..63
            if (md) dn = __ffsll(md) - 1;
            else if (hi) dn = (64 - i) + (__ffs(hi) - 1);
        } else {
            int ih = i - 64;
            unsigned int mu = hi & (0xFFFFFFFFu >> (31 - ih));         // rows 64..i
            if (mu) up = ih - (31 - __clz(mu));
            else if (lo) up = i - (63 - __clzll(lo));
            unsigned int md = hi >> ih;                                // rows i..95
            if (md) dn = __ffs(md) - 1;
        }
        int d = (up < dn) ? up : dn;
        gq[p] = (d < HH) ? (float)(d * d) : BIGF;
    }
    __syncthreads();

    // ---- P4: row pass, EXACT early-exit outward scan, gated on maskO ----
    // Only masked pixels feed the max, so skip unmasked entirely.
    // best = min over o of g[j +- o] + o^2; stop once o^2 >= best.
    float m = -BIGF;
    for (int p4 = tid; p4 < OROWS * WW; p4 += 1024) {
        int p = pix0 + p4;
        if (!maskO[p]) continue;
        int i = p / WW;
        int j = p - i * WW;
        const float* grow = &gq[i * WW];
        float best = grow[j];
        for (int o = 1; o < WW; ++o) {
            float o2 = (float)(o * o);
            if (o2 >= best) break;
            int jl = j - o, jr = j + o;
            if (jl >= 0)  best = fminf(best, grow[jl] + o2);
            if (jr < WW)  best = fminf(best, grow[jr] + o2);
        }
        m = fmaxf(m, best);
    }
    // block max-reduce (16 waves)
    #pragma unroll
    for (int off = 32; off > 0; off >>= 1) m = fmaxf(m, __shfl_down(m, off));
    const int wid = tid >> 6, lid = tid & 63;
    if (lid == 0) red[wid] = m;
    __syncthreads();
    if (tid == 0) {
        float mm = red[0];
        #pragma unroll
        for (int w = 1; w < 16; ++w) mm = fmaxf(mm, red[w]);
        partial[blk] = mm;
    }
}

// ---------------------------------------------------------------------------
// K2: combine 64 partials -> mean over batches of sqrt(max(fwd,bwd,0))
// Wave-parallel: lane t owns partial[t]; xor-shuffle max over octants (1,2,4)
// then over direction (8); lanes 0/16/32/48 hold per-batch results.
// ---------------------------------------------------------------------------
__global__ void k_fin(const float* __restrict__ partial, float* __restrict__ outv) {
    const int t = threadIdx.x;     // 64 threads = 1 wave
    float m = partial[t];
    m = fmaxf(m, __shfl_xor(m, 1));
    m = fmaxf(m, __shfl_xor(m, 2));
    m = fmaxf(m, __shfl_xor(m, 4));   // max over 8 octants (groups 8-aligned)
    m = fmaxf(m, __shfl_xor(m, 8));   // max(fwd, bwd) within batch
    float s = sqrtf(fmaxf(m, 0.0f));
    float s0 = __shfl(s, 0), s1 = __shfl(s, 16), s2 = __shfl(s, 32), s3 = __shfl(s, 48);
    if (t == 0) outv[0] = (s0 + s1 + s2 + s3) * 0.25f;
}

// ---------------------------------------------------------------------------
extern "C" void kernel_launch(void* const* d_in, const int* in_sizes, int n_in,
                              void* d_out, int out_size, void* d_ws, size_t ws_size,
                              hipStream_t stream) {
    const float* output = (const float*)d_in[0];   // [B,C,H,W] fp32
    const int* target   = (const int*)d_in[1];     // [B,H,W] int32
    float* outv         = (float*)d_out;           // scalar fp32
    float* partial      = (float*)d_ws;            // 64 floats

    k_fused<<<64, 1024, 0, stream>>>(output, target, partial);
    k_fin<<<1, 64, 0, stream>>>(partial, outv);
}